// Round 2
// baseline (374.868 us; speedup 1.0000x reference)
//
#include <hip/hip_runtime.h>
#include <math.h>

// ---------------- sizes ----------------
#define DD 256
#define KK 512
#define LL 64
#define BB 8
#define SS 16
#define F_LOG2PI 1.83787706641f
#define PER_I 16777216u   // i-stride in per-half eps flat index (64*16*64*256)

typedef float v2f __attribute__((ext_vector_type(2)));

// ---------------- threefry2x32 (JAX-compatible) ----------------
struct U2 { unsigned x, y; };

__host__ __device__ constexpr U2 tf2x32(unsigned k0, unsigned k1, unsigned c0, unsigned c1) {
  unsigned ks2 = k0 ^ k1 ^ 0x1BD11BDAu;
  unsigned x0 = c0 + k0;
  unsigned x1 = c1 + k1;
#define TFR(r) { x0 += x1; x1 = (x1 << (r)) | (x1 >> (32 - (r))); x1 ^= x0; }
  TFR(13) TFR(15) TFR(26) TFR(6)   x0 += k1;  x1 += ks2 + 1u;
  TFR(17) TFR(29) TFR(16) TFR(24)  x0 += ks2; x1 += k0 + 2u;
  TFR(13) TFR(15) TFR(26) TFR(6)   x0 += k0;  x1 += k1 + 3u;
  TFR(17) TFR(29) TFR(16) TFR(24)  x0 += k1;  x1 += ks2 + 4u;
  TFR(13) TFR(15) TFR(26) TFR(6)   x0 += ks2; x1 += k0 + 5u;
#undef TFR
  return U2{x0, x1};
}

// Single-instruction rotate-left via v_alignbit_b32.
__device__ inline unsigned rotl(unsigned x, unsigned r) {
  return __builtin_amdgcn_alignbit(x, x, 32u - r);
}

// Threefry with c0=0 and k1 pre-folded into the counter (x1 = c1 + k1).
// Mid-stream key injections folded into the next round's add (v_add3_u32).
// Returns x0 ^ x1 (the JAX partitionable 32-bit draw).
__device__ inline unsigned tf_fold(unsigned k0, unsigned k1, unsigned ks2, unsigned x1) {
  unsigned x0 = k0;
#define TFR(r)            { x0 += x1; x1 = rotl(x1, r); x1 ^= x0; }
#define TFRI(r, kA, kB)   { x1 += (kB); x0 = x0 + (kA) + x1; x1 = rotl(x1, r); x1 ^= x0; }
  TFR(13u) TFR(15u) TFR(26u) TFR(6u)
  TFRI(17u, k1, ks2 + 1u)
  TFR(29u) TFR(16u) TFR(24u)
  TFRI(13u, ks2, k0 + 2u)
  TFR(15u) TFR(26u) TFR(6u)
  TFRI(17u, k0, k1 + 3u)
  TFR(29u) TFR(16u) TFR(24u)
  TFRI(13u, k1, ks2 + 4u)
  TFR(15u) TFR(26u) TFR(6u)
  x0 += ks2; x1 += k0 + 5u;
#undef TFR
#undef TFRI
  return x0 ^ x1;
}

// Packed fma helper: <2 x float> fma -> v_pk_fma_f32 on gfx90a+.
__device__ inline v2f pkfma(v2f a, v2f b, v2f c) {
#if __has_builtin(__builtin_elementwise_fma)
  return __builtin_elementwise_fma(a, b, c);
#else
  v2f r; r.x = fmaf(a.x, b.x, c.x); r.y = fmaf(a.y, b.y, c.y); return r;
#endif
}

// Two draws at once: bits -> {p*u, p*u}  (eps = sqrt2*p*u; sqrt2 folded into
// caller's scale). Low erfinv branch packed across the pair; high branch
// (w>=5) behind a wave-uniform __any, itself pk-paired.
__device__ inline v2f normal_pu2(unsigned b0, unsigned b1) {
  v2f fv;
  fv.x = __uint_as_float(__builtin_amdgcn_alignbit(128u, b0, 9u)); // (b>>9)|0x40000000
  fv.y = __uint_as_float(__builtin_amdgcn_alignbit(128u, b1, 9u));
  v2f uv = fv + (v2f){-3.0f, -3.0f};             // 2f-1 in [-1,1)
#if __has_builtin(__builtin_elementwise_max)
  uv = __builtin_elementwise_max(uv, (v2f){-0.99999994f, -0.99999994f});
#else
  uv.x = fmaxf(-0.99999994f, uv.x);
  uv.y = fmaxf(-0.99999994f, uv.y);
#endif
  v2f tv = pkfma(-uv, uv, (v2f){1.0f, 1.0f});    // 1 - u*u
  v2f lv;
  lv.x = __log2f(tv.x);
  lv.y = __log2f(tv.y);
  const v2f nln2 = {-0.69314718056f, -0.69314718056f};
  v2f wx = pkfma(lv, nln2, (v2f){-2.5f, -2.5f}); // w - 2.5
  v2f p; p.x = 2.81022636e-08f; p.y = 2.81022636e-08f;
  p = pkfma(p, wx, (v2f){ 3.43273939e-07f,  3.43273939e-07f});
  p = pkfma(p, wx, (v2f){-3.5233877e-06f,  -3.5233877e-06f});
  p = pkfma(p, wx, (v2f){-4.39150654e-06f, -4.39150654e-06f});
  p = pkfma(p, wx, (v2f){ 0.00021858087f,   0.00021858087f});
  p = pkfma(p, wx, (v2f){-0.00125372503f,  -0.00125372503f});
  p = pkfma(p, wx, (v2f){-0.00417768164f,  -0.00417768164f});
  p = pkfma(p, wx, (v2f){ 0.246640727f,     0.246640727f});
  p = pkfma(p, wx, (v2f){ 1.50140941f,      1.50140941f});
  v2f pu = p * uv;
  if (__any(fmaxf(wx.x, wx.y) >= 2.5f)) {        // any lane needs high branch
    v2f wv = lv * nln2;                          // w (same rounding as before)
    v2f sy;
    sy.x = __builtin_amdgcn_sqrtf(wv.x) - 3.0f;
    sy.y = __builtin_amdgcn_sqrtf(wv.y) - 3.0f;
    v2f q; q.x = -0.000200214257f; q.y = -0.000200214257f;
    q = pkfma(q, sy, (v2f){ 0.000100950558f,  0.000100950558f});
    q = pkfma(q, sy, (v2f){ 0.00134934322f,   0.00134934322f});
    q = pkfma(q, sy, (v2f){-0.00367342844f,  -0.00367342844f});
    q = pkfma(q, sy, (v2f){ 0.00573950773f,   0.00573950773f});
    q = pkfma(q, sy, (v2f){-0.0076224613f,   -0.0076224613f});
    q = pkfma(q, sy, (v2f){ 0.00943887047f,   0.00943887047f});
    q = pkfma(q, sy, (v2f){ 1.00167406f,      1.00167406f});
    q = pkfma(q, sy, (v2f){ 2.83297682f,      2.83297682f});
    v2f qu = q * uv;
    pu.x = (wx.x < 2.5f) ? pu.x : qu.x;
    pu.y = (wx.y < 2.5f) ? pu.y : qu.y;
  }
  return pu;
}

// ---------------- kernels ----------------

// Fused: counting-sort (recomputed per block, LDS-local) + prototype fusion
// + accbuf/lmacc zeroing. Block 0 publishes pos/lmap for k_tl.
// pq[.w] doubles as the per-(h,lq) completion counter for k_tl's fused
// epilogue -- zeroed here every launch.
__global__ void k_protos(const float* __restrict__ P, const float* __restrict__ he_p,
                         const int* __restrict__ labels, float4* __restrict__ pq,
                         float* __restrict__ cl, float4* __restrict__ accz,
                         float4* __restrict__ lmz, int* __restrict__ pos,
                         int* __restrict__ lmap) {
  int hb = blockIdx.x;             // h*64 + l
  int h = hb >> 6, l = hb & 63;
  int d = threadIdx.x;

  // zero accbuf (131072 float4 / 128 blocks / 256 thr = 4 each) and
  // lmacc (8192 float4: first 8192 global threads take one each)
  {
    float4 z; z.x = z.y = z.z = z.w = 0.0f;
    float4* base = accz + (hb * 256 + d) * 4;
#pragma unroll
    for (int j = 0; j < 4; ++j) base[j] = z;
    int gtid = hb * 256 + d;
    if (gtid < 8192) lmz[gtid] = z;
  }

  // ---- LDS counting-sort of balanced labels (robust to int64 labels) ----
  __shared__ int lab[512];
  __shared__ int cnt[64];
  __shared__ int mode;
  __shared__ int posl[512];
  if (d < 64) cnt[d] = 0;
  if (d == 0) mode = 0;
  __syncthreads();
  int v0 = labels[d], v1 = labels[d + 256];
  atomicAdd(&cnt[v0 & 63], 1);
  atomicAdd(&cnt[v1 & 63], 1);
  __syncthreads();
  if (d < 64 && cnt[d] != 8) mode = 1;   // benign same-value race
  __syncthreads();
  if (mode) { v0 = labels[2 * d]; v1 = labels[2 * (d + 256)]; }  // int64 LE low words
  lab[d] = v0 & 63; lab[d + 256] = v1 & 63;
  __syncthreads();
#pragma unroll
  for (int e = d; e < 512; e += 256) {
    int c = lab[e], o = 0;
    for (int j = 0; j < e; ++j) o += (lab[j] == c);
    posl[c * 8 + o] = e;               // idx of o-th occurrence of class c
  }
  __syncthreads();
  if (hb == 0) {                        // publish for k_tl
    pos[d] = posl[d]; pos[d + 256] = posl[d + 256];
    if (d < 64) lmap[d] = d;
  }

  // ---- prototype fusion ----
  float eps_var = expf(he_p[0]);
  int soff = h ? 0 : 4;            // support rows for this half
  float sinv = 0.f, sminv = 0.f;
#pragma unroll
  for (int j = 0; j < 4; ++j) {
    int row = posl[l * 8 + soff + j];
    float m = P[row * KK + d];
    float hh = P[row * KK + DD + d];
    float vv = eps_var + expf(hh);
    float iv = 1.0f / vv;
    sinv += iv; sminv += m * iv;
  }
  float nv = 1.0f / sinv;
  float nm = nv * sminv;
  float ev = eps_var + nv;         // exp(h_proto)
  float4 rec; rec.x = nm; rec.y = ev; rec.z = 1.0f / ev; rec.w = 0.0f;  // .w: counter slot
  pq[(h * 256 + d) * 64 + l] = rec;
  float t = F_LOG2PI + __logf(ev);
  for (int off = 32; off; off >>= 1) t += __shfl_xor(t, off);
  __shared__ float red[4];
  int w = d >> 6, lane = d & 63;
  if (lane == 0) red[w] = t;
  __syncthreads();
  if (d == 0) cl[hb] = red[0] + red[1] + red[2] + red[3];
}

// Hot kernel: block=(h, lq, dchunk of 16). wave w = query i, lane = lp.
// 16 independent threefry chains processed as 8 pk-paired draws; dd-loop
// software-pipelined (prefetch pr/qv one iteration ahead). The last block of
// each (h,lq) group (16 chunk blocks, counted via pq[h][0][lq].w) runs the
// fused epilogue (former k_final) for its 4 g's.
__global__ __launch_bounds__(256, 8) void k_tl(const float* __restrict__ P,
    const int* __restrict__ pos, const float4* __restrict__ pq,
    float* __restrict__ accbuf, float* __restrict__ lmacc,
    const float* __restrict__ cl, float* __restrict__ out) {
  constexpr U2 S1 = tf2x32(0u, 42u, 0u, 0u);  // foldlike split of key(42)
  constexpr U2 S2 = tf2x32(0u, 42u, 0u, 1u);
  int bb = blockIdx.x;             // h*1024 + lq*16 + chunk
  int h = bb >> 10;
  int lq = (bb >> 4) & 63;
  int chunk = bb & 15;
  int t = threadIdx.x;

  __shared__ float2 q[4 * 256 + 8];  // [i][d] = {m, exp(h)}; +8 pad for prefetch
#pragma unroll
  for (int i = 0; i < 4; ++i) {
    int row = pos[lq * 8 + h * 4 + i];
    float2 rec;
    rec.x = P[row * KK + t];
    rec.y = expf(P[row * KK + DD + t]);
    q[i * 256 + t] = rec;
  }
  __syncthreads();

  int w = t >> 6, lane = t & 63;   // w = query i, lane = lp
  unsigned k0 = h ? S2.x : S1.x;
  unsigned k1 = h ? S2.y : S1.y;
  unsigned ks2 = k0 ^ k1 ^ 0x1BD11BDAu;
  // eps flat idx (per half) = i*PER_I + lq*262144 + s*16384 + lp*256 + d
  // k1 folded into the counter base (threefry x1 init = c1 + k1).
  unsigned ebk = (unsigned)w * PER_I + (unsigned)lq * 262144u +
                 (unsigned)lane * 256u + (unsigned)chunk * 16u + k1;
  const float2* qd = &q[w * 256];
  const float4* pp = pq + (h * 256 + chunk * 16) * 64 + lane;
  int g = h * 4 + w;
  float* dst = accbuf + ((g * 64 + lq) * 16) * 64 + lane;

  v2f acc2[8];
#pragma unroll
  for (int sp = 0; sp < 8; ++sp) { acc2[sp].x = 0.0f; acc2[sp].y = 0.0f; }
  float lmpart = 0.0f;             // partial of sum_d(log vs + diff^2/vs)

  float4 pr = pp[0];               // software pipeline: current pr/qv
  float2 qv = qd[chunk * 16];
#pragma unroll 1
  for (int dd = 0; dd < 16; ++dd) {
    float4 prn = pp[(dd + 1) * 64];        // one-past-end lands in cl/pos region: harmless
    float2 qvn = qd[chunk * 16 + dd + 1];  // one-past-end in LDS pad
    float vs  = qv.y + pr.y;
    float ivs = __builtin_amdgcn_rcpf(vs);
    float evs = pr.y * ivs;            // ev/vs
    float sivp = __builtin_amdgcn_sqrtf(pr.z);
    float dif = qv.x - pr.x;
    lmpart += __logf(vs) + dif * dif * ivs;              // lm term
    float A = dif * evs * sivp;                          // sign irrelevant (squared)
    float S = __builtin_amdgcn_sqrtf(qv.y * evs) * sivp * 1.41421356f; // sqrt2 folded
    v2f Av; Av.x = A; Av.y = A;
    v2f Sv; Sv.x = S; Sv.y = S;
    unsigned ebkd = ebk + (unsigned)dd;
#pragma unroll
    for (int sp = 0; sp < 8; ++sp) {
      unsigned bits0 = tf_fold(k0, k1, ks2, ebkd + (unsigned)(2 * sp) * 16384u);
      unsigned bits1 = tf_fold(k0, k1, ks2, ebkd + (unsigned)(2 * sp + 1) * 16384u);
      v2f pu = normal_pu2(bits0, bits1);
      v2f diff = pkfma(Sv, pu, Av);
      acc2[sp] = pkfma(diff, diff, acc2[sp]);
    }
    pr = prn; qv = qvn;
  }
#pragma unroll
  for (int sp = 0; sp < 8; ++sp) {
    atomicAdd(dst + (2 * sp) * 64, acc2[sp].x);
    atomicAdd(dst + (2 * sp + 1) * 64, acc2[sp].y);
  }
  atomicAdd(lmacc + (g * 64 + lq) * 64 + lane, lmpart);

  // ---- completion handshake: last of 16 chunk-blocks runs the epilogue ----
  __threadfence();
  __syncthreads();
  __shared__ int oldc;
  if (t == 0) {
    int* cw = (int*)pq + (((h * 256) * 64 + lq) * 4 + 3);  // pq[h][0][lq].w
    oldc = atomicAdd(cw, 1);
  }
  __syncthreads();
  if (oldc != 15) return;

  // ---- fused epilogue (former k_final): wave w handles g = h*4+w ----
  __shared__ float lseb[4][16];
  float clv = cl[h * 64 + lane];
  // read partials through the atomic RMW path (chip-coherent, same path the
  // contributions took); all 16 issued up front so they pipeline.
  float av[16];
#pragma unroll
  for (int s = 0; s < 16; ++s) av[s] = atomicAdd(dst + s * 64, 0.0f);
#pragma unroll
  for (int s = 0; s < 16; ++s) {
    float tlv = -0.5f * (clv + av[s]);
    float mx = tlv;
    for (int off = 32; off; off >>= 1) mx = fmaxf(mx, __shfl_xor(mx, off));
    float se = expf(tlv - mx);
    for (int off = 32; off; off >>= 1) se += __shfl_xor(se, off);
    if (lane == 0) lseb[w][s] = mx + __logf(se);
  }
  __syncthreads();
  float a2 = (lane < 16) ? -lseb[w][lane] : -INFINITY;
  float mx2 = a2;
  for (int off = 32; off; off >>= 1) mx2 = fmaxf(mx2, __shfl_xor(mx2, off));
  float e2 = (lane < 16) ? expf(a2 - mx2) : 0.0f;
  for (int off = 32; off; off >>= 1) e2 += __shfl_xor(e2, off);
  float mc = mx2 + __logf(e2) - 2.7725887f;   // - log(16)
  float lmw = atomicAdd(lmacc + (g * 64 + lq) * 64 + lane, 0.0f);
  float lmv = -0.5f * (256.0f * F_LOG2PI + lmw);
  int row = pos[lq * 8 + g];
  out[row * 64 + lane] = lmv + mc;             // lmap is identity
}

// ---------------- launch ----------------
extern "C" void kernel_launch(void* const* d_in, const int* in_sizes, int n_in,
                              void* d_out, int out_size, void* d_ws, size_t ws_size,
                              hipStream_t stream) {
  (void)in_sizes; (void)n_in; (void)out_size; (void)ws_size;
  const float* P      = (const float*)d_in[0];   // (512, 512) f32
  const float* he     = (const float*)d_in[1];   // scalar
  const int*   labels = (const int*)d_in[2];     // (512,) int
  float* out = (float*)d_out;                    // (512, 64) f32

  float* ws = (float*)d_ws;
  float* accbuf = ws;                   // [8][64][16][64] = 524288 floats (2 MB)
  float* lmacc  = ws + 524288;          // [8][64][64] = 32768 floats
  float4* pq = (float4*)(ws + 557056);  // [2][256][64] float4 = 131072 floats
  float* cl  = ws + 688128;             // [2][64]
  int*   pos = (int*)(ws + 688256);     // [512]
  int*   lmp = pos + 512;               // [64]

  hipLaunchKernelGGL(k_protos, dim3(128),  dim3(256), 0, stream, P, he, labels, pq, cl,
                     (float4*)accbuf, (float4*)lmacc, pos, lmp);
  hipLaunchKernelGGL(k_tl,     dim3(2048), dim3(256), 0, stream, P, pos, pq, accbuf, lmacc,
                     cl, out);
}

// Round 3
// 364.933 us; speedup vs baseline: 1.0272x; 1.0272x over previous
//
#include <hip/hip_runtime.h>
#include <math.h>

// ---------------- sizes ----------------
#define DD 256
#define KK 512
#define LL 64
#define BB 8
#define SS 16
#define F_LOG2PI 1.83787706641f
#define PER_I 16777216u   // i-stride in per-half eps flat index (64*16*64*256)

typedef float v2f __attribute__((ext_vector_type(2)));

// ---------------- threefry2x32 (JAX-compatible) ----------------
struct U2 { unsigned x, y; };

__host__ __device__ constexpr U2 tf2x32(unsigned k0, unsigned k1, unsigned c0, unsigned c1) {
  unsigned ks2 = k0 ^ k1 ^ 0x1BD11BDAu;
  unsigned x0 = c0 + k0;
  unsigned x1 = c1 + k1;
#define TFR(r) { x0 += x1; x1 = (x1 << (r)) | (x1 >> (32 - (r))); x1 ^= x0; }
  TFR(13) TFR(15) TFR(26) TFR(6)   x0 += k1;  x1 += ks2 + 1u;
  TFR(17) TFR(29) TFR(16) TFR(24)  x0 += ks2; x1 += k0 + 2u;
  TFR(13) TFR(15) TFR(26) TFR(6)   x0 += k0;  x1 += k1 + 3u;
  TFR(17) TFR(29) TFR(16) TFR(24)  x0 += k1;  x1 += ks2 + 4u;
  TFR(13) TFR(15) TFR(26) TFR(6)   x0 += ks2; x1 += k0 + 5u;
#undef TFR
  return U2{x0, x1};
}

// Single-instruction rotate-left via v_alignbit_b32.
__device__ inline unsigned rotl(unsigned x, unsigned r) {
  return __builtin_amdgcn_alignbit(x, x, 32u - r);
}

// Threefry with c0=0 and k1 pre-folded into the counter (x1 = c1 + k1).
// Mid-stream key injections folded into the next round's add (v_add3_u32).
// Returns x0 ^ x1 (the JAX partitionable 32-bit draw).
__device__ inline unsigned tf_fold(unsigned k0, unsigned k1, unsigned ks2, unsigned x1) {
  unsigned x0 = k0;
#define TFR(r)            { x0 += x1; x1 = rotl(x1, r); x1 ^= x0; }
#define TFRI(r, kA, kB)   { x1 += (kB); x0 = x0 + (kA) + x1; x1 = rotl(x1, r); x1 ^= x0; }
  TFR(13u) TFR(15u) TFR(26u) TFR(6u)
  TFRI(17u, k1, ks2 + 1u)
  TFR(29u) TFR(16u) TFR(24u)
  TFRI(13u, ks2, k0 + 2u)
  TFR(15u) TFR(26u) TFR(6u)
  TFRI(17u, k0, k1 + 3u)
  TFR(29u) TFR(16u) TFR(24u)
  TFRI(13u, k1, ks2 + 4u)
  TFR(15u) TFR(26u) TFR(6u)
  x0 += ks2; x1 += k0 + 5u;
#undef TFR
#undef TFRI
  return x0 ^ x1;
}

// Packed fma helper: <2 x float> fma -> v_pk_fma_f32 on gfx90a+.
__device__ inline v2f pkfma(v2f a, v2f b, v2f c) {
#if __has_builtin(__builtin_elementwise_fma)
  return __builtin_elementwise_fma(a, b, c);
#else
  v2f r; r.x = fmaf(a.x, b.x, c.x); r.y = fmaf(a.y, b.y, c.y); return r;
#endif
}

// Two draws at once: bits -> {p*u, p*u}  (eps = sqrt2*p*u; sqrt2 folded into
// caller's scale). Low erfinv branch packed across the pair; high branch
// (w>=5) behind a wave-uniform __any, itself pk-paired.
__device__ inline v2f normal_pu2(unsigned b0, unsigned b1) {
  v2f fv;
  fv.x = __uint_as_float(__builtin_amdgcn_alignbit(128u, b0, 9u)); // (b>>9)|0x40000000
  fv.y = __uint_as_float(__builtin_amdgcn_alignbit(128u, b1, 9u));
  v2f uv = fv + (v2f){-3.0f, -3.0f};             // 2f-1 in [-1,1)
#if __has_builtin(__builtin_elementwise_max)
  uv = __builtin_elementwise_max(uv, (v2f){-0.99999994f, -0.99999994f});
#else
  uv.x = fmaxf(-0.99999994f, uv.x);
  uv.y = fmaxf(-0.99999994f, uv.y);
#endif
  v2f tv = pkfma(-uv, uv, (v2f){1.0f, 1.0f});    // 1 - u*u
  v2f lv;
  lv.x = __log2f(tv.x);
  lv.y = __log2f(tv.y);
  const v2f nln2 = {-0.69314718056f, -0.69314718056f};
  v2f wx = pkfma(lv, nln2, (v2f){-2.5f, -2.5f}); // w - 2.5
  v2f p; p.x = 2.81022636e-08f; p.y = 2.81022636e-08f;
  p = pkfma(p, wx, (v2f){ 3.43273939e-07f,  3.43273939e-07f});
  p = pkfma(p, wx, (v2f){-3.5233877e-06f,  -3.5233877e-06f});
  p = pkfma(p, wx, (v2f){-4.39150654e-06f, -4.39150654e-06f});
  p = pkfma(p, wx, (v2f){ 0.00021858087f,   0.00021858087f});
  p = pkfma(p, wx, (v2f){-0.00125372503f,  -0.00125372503f});
  p = pkfma(p, wx, (v2f){-0.00417768164f,  -0.00417768164f});
  p = pkfma(p, wx, (v2f){ 0.246640727f,     0.246640727f});
  p = pkfma(p, wx, (v2f){ 1.50140941f,      1.50140941f});
  v2f pu = p * uv;
  if (__any(fmaxf(wx.x, wx.y) >= 2.5f)) {        // any lane needs high branch
    v2f wv = lv * nln2;                          // w (same rounding as before)
    v2f sy;
    sy.x = __builtin_amdgcn_sqrtf(wv.x) - 3.0f;
    sy.y = __builtin_amdgcn_sqrtf(wv.y) - 3.0f;
    v2f q; q.x = -0.000200214257f; q.y = -0.000200214257f;
    q = pkfma(q, sy, (v2f){ 0.000100950558f,  0.000100950558f});
    q = pkfma(q, sy, (v2f){ 0.00134934322f,   0.00134934322f});
    q = pkfma(q, sy, (v2f){-0.00367342844f,  -0.00367342844f});
    q = pkfma(q, sy, (v2f){ 0.00573950773f,   0.00573950773f});
    q = pkfma(q, sy, (v2f){-0.0076224613f,   -0.0076224613f});
    q = pkfma(q, sy, (v2f){ 0.00943887047f,   0.00943887047f});
    q = pkfma(q, sy, (v2f){ 1.00167406f,      1.00167406f});
    q = pkfma(q, sy, (v2f){ 2.83297682f,      2.83297682f});
    v2f qu = q * uv;
    pu.x = (wx.x < 2.5f) ? pu.x : qu.x;
    pu.y = (wx.y < 2.5f) ? pu.y : qu.y;
  }
  return pu;
}

// ---------------- kernels ----------------

// Fused: counting-sort (recomputed per block, LDS-local) + prototype fusion
// + accbuf/lmacc zeroing. Block 0 publishes pos for k_tl.
// pq[.w] doubles as the per-(h,lq) completion counter for k_tl's fused
// epilogue -- zeroed here every launch.
__global__ void k_protos(const float* __restrict__ P, const float* __restrict__ he_p,
                         const int* __restrict__ labels, float4* __restrict__ pq,
                         float* __restrict__ cl, float4* __restrict__ accz,
                         float4* __restrict__ lmz, int* __restrict__ pos,
                         int* __restrict__ lmap) {
  int hb = blockIdx.x;             // h*64 + l
  int h = hb >> 6, l = hb & 63;
  int d = threadIdx.x;

  // zero accbuf (131072 float4 / 128 blocks / 256 thr = 4 each) and
  // lmacc (8192 float4: first 8192 global threads take one each)
  {
    float4 z; z.x = z.y = z.z = z.w = 0.0f;
    float4* base = accz + (hb * 256 + d) * 4;
#pragma unroll
    for (int j = 0; j < 4; ++j) base[j] = z;
    int gtid = hb * 256 + d;
    if (gtid < 8192) lmz[gtid] = z;
  }

  // ---- LDS counting-sort of balanced labels (robust to int64 labels) ----
  __shared__ int lab[512];
  __shared__ int cnt[64];
  __shared__ int mode;
  __shared__ int posl[512];
  if (d < 64) cnt[d] = 0;
  if (d == 0) mode = 0;
  __syncthreads();
  int v0 = labels[d], v1 = labels[d + 256];
  atomicAdd(&cnt[v0 & 63], 1);
  atomicAdd(&cnt[v1 & 63], 1);
  __syncthreads();
  if (d < 64 && cnt[d] != 8) mode = 1;   // benign same-value race
  __syncthreads();
  if (mode) { v0 = labels[2 * d]; v1 = labels[2 * (d + 256)]; }  // int64 LE low words
  lab[d] = v0 & 63; lab[d + 256] = v1 & 63;
  __syncthreads();
#pragma unroll
  for (int e = d; e < 512; e += 256) {
    int c = lab[e], o = 0;
    for (int j = 0; j < e; ++j) o += (lab[j] == c);
    posl[c * 8 + o] = e;               // idx of o-th occurrence of class c
  }
  __syncthreads();
  if (hb == 0) {                        // publish for k_tl
    pos[d] = posl[d]; pos[d + 256] = posl[d + 256];
    if (d < 64) lmap[d] = d;
  }

  // ---- prototype fusion ----
  float eps_var = expf(he_p[0]);
  int soff = h ? 0 : 4;            // support rows for this half
  float sinv = 0.f, sminv = 0.f;
#pragma unroll
  for (int j = 0; j < 4; ++j) {
    int row = posl[l * 8 + soff + j];
    float m = P[row * KK + d];
    float hh = P[row * KK + DD + d];
    float vv = eps_var + expf(hh);
    float iv = 1.0f / vv;
    sinv += iv; sminv += m * iv;
  }
  float nv = 1.0f / sinv;
  float nm = nv * sminv;
  float ev = eps_var + nv;         // exp(h_proto)
  // .z = rsqrt(ev) so k_tl needs no sqrt; .w = completion-counter slot.
  float4 rec; rec.x = nm; rec.y = ev;
  rec.z = __builtin_amdgcn_rcpf(__builtin_amdgcn_sqrtf(ev));
  rec.w = 0.0f;
  pq[(h * 256 + d) * 64 + l] = rec;
  float t = F_LOG2PI + __logf(ev);
  for (int off = 32; off; off >>= 1) t += __shfl_xor(t, off);
  __shared__ float red[4];
  int w = d >> 6, lane = d & 63;
  if (lane == 0) red[w] = t;
  __syncthreads();
  if (d == 0) cl[hb] = red[0] + red[1] + red[2] + red[3];
}

// Hot kernel: block=(h, lq, dchunk of 16). wave w = query i, lane = lp.
// 16 independent threefry chains processed as 8 pk-paired draws; dd-loop
// software-pipelined (prefetch pr/qv one iteration ahead). The last block of
// each (h,lq) group (16 chunk blocks, counted via pq[h][0][lq].w) runs the
// fused epilogue (former k_final) for its 4 g's.
// NO __threadfence here: __syncthreads' implicit s_waitcnt vmcnt(0) drains
// the device-scope atomics before the counter increment (R2's threadfence
// was a per-block L2 writeback -- 30us regression).
__global__ __launch_bounds__(256, 8) void k_tl(const float* __restrict__ P,
    const int* __restrict__ pos, const float4* __restrict__ pq,
    float* __restrict__ accbuf, float* __restrict__ lmacc,
    const float* __restrict__ cl, float* __restrict__ out) {
  constexpr U2 S1 = tf2x32(0u, 42u, 0u, 0u);  // foldlike split of key(42)
  constexpr U2 S2 = tf2x32(0u, 42u, 0u, 1u);
  int bb = blockIdx.x;             // h*1024 + lq*16 + chunk
  int h = bb >> 10;
  int lq = (bb >> 4) & 63;
  int chunk = bb & 15;
  int t = threadIdx.x;

  __shared__ float2 q[4 * 256 + 8];  // [i][d] = {m, exp(h)}; +8 pad for prefetch
#pragma unroll
  for (int i = 0; i < 4; ++i) {
    int row = pos[lq * 8 + h * 4 + i];
    float2 rec;
    rec.x = P[row * KK + t];
    rec.y = expf(P[row * KK + DD + t]);
    q[i * 256 + t] = rec;
  }
  __syncthreads();

  int w = t >> 6, lane = t & 63;   // w = query i, lane = lp
  unsigned k0 = h ? S2.x : S1.x;
  unsigned k1 = h ? S2.y : S1.y;
  unsigned ks2 = k0 ^ k1 ^ 0x1BD11BDAu;
  // eps flat idx (per half) = i*PER_I + lq*262144 + s*16384 + lp*256 + d
  // k1 folded into the counter base (threefry x1 init = c1 + k1).
  unsigned ebk = (unsigned)w * PER_I + (unsigned)lq * 262144u +
                 (unsigned)lane * 256u + (unsigned)chunk * 16u + k1;
  const float2* qd = &q[w * 256];
  const float4* pp = pq + (h * 256 + chunk * 16) * 64 + lane;
  int g = h * 4 + w;
  float* dst = accbuf + ((g * 64 + lq) * 16) * 64 + lane;

  v2f acc2[8];
#pragma unroll
  for (int sp = 0; sp < 8; ++sp) { acc2[sp].x = 0.0f; acc2[sp].y = 0.0f; }
  float lmpart = 0.0f;             // partial of sum_d(log vs + diff^2/vs)

  float4 pr = pp[0];               // software pipeline: current pr/qv
  float2 qv = qd[chunk * 16];
#pragma unroll 1
  for (int dd = 0; dd < 16; ++dd) {
    float4 prn = pp[(dd + 1) * 64];        // one-past-end lands in cl region: harmless
    float2 qvn = qd[chunk * 16 + dd + 1];  // one-past-end in LDS pad
    float vs  = qv.y + pr.y;
    float ivs = __builtin_amdgcn_rcpf(vs);
    float evs = pr.y * ivs;            // ev/vs
    float sivp = pr.z;                 // rsqrt(ev), precomputed in k_protos
    float dif = qv.x - pr.x;
    lmpart += __logf(vs) + dif * dif * ivs;              // lm term
    float A = dif * evs * sivp;                          // sign irrelevant (squared)
    float S = __builtin_amdgcn_sqrtf(qv.y * evs) * sivp * 1.41421356f; // sqrt2 folded
    v2f Av; Av.x = A; Av.y = A;
    v2f Sv; Sv.x = S; Sv.y = S;
    unsigned ebkd = ebk + (unsigned)dd;
#pragma unroll
    for (int sp = 0; sp < 8; ++sp) {
      unsigned bits0 = tf_fold(k0, k1, ks2, ebkd + (unsigned)(2 * sp) * 16384u);
      unsigned bits1 = tf_fold(k0, k1, ks2, ebkd + (unsigned)(2 * sp + 1) * 16384u);
      v2f pu = normal_pu2(bits0, bits1);
      v2f diff = pkfma(Sv, pu, Av);
      acc2[sp] = pkfma(diff, diff, acc2[sp]);
    }
    pr = prn; qv = qvn;
  }
#pragma unroll
  for (int sp = 0; sp < 8; ++sp) {
    atomicAdd(dst + (2 * sp) * 64, acc2[sp].x);
    atomicAdd(dst + (2 * sp + 1) * 64, acc2[sp].y);
  }
  atomicAdd(lmacc + (g * 64 + lq) * 64 + lane, lmpart);

  // ---- completion handshake: last of 16 chunk-blocks runs the epilogue ----
  // __syncthreads drains each wave's outstanding atomics (implicit vmcnt(0))
  // before any thread proceeds to the counter increment.
  __syncthreads();
  __shared__ int oldc;
  if (t == 0) {
    int* cw = (int*)pq + (((h * 256) * 64 + lq) * 4 + 3);  // pq[h][0][lq].w
    oldc = atomicAdd(cw, 1);
  }
  __syncthreads();
  if (oldc != 15) return;

  // ---- fused epilogue (former k_final): wave w handles g = h*4+w ----
  __shared__ float lseb[4][16];
  float clv = cl[h * 64 + lane];
  // read partials through the atomic RMW path (chip-coherent, same path the
  // contributions took); all 16 issued up front so they pipeline.
  float av[16];
#pragma unroll
  for (int s = 0; s < 16; ++s) av[s] = atomicAdd(dst + s * 64, 0.0f);
#pragma unroll
  for (int s = 0; s < 16; ++s) {
    float tlv = -0.5f * (clv + av[s]);
    float mx = tlv;
    for (int off = 32; off; off >>= 1) mx = fmaxf(mx, __shfl_xor(mx, off));
    float se = expf(tlv - mx);
    for (int off = 32; off; off >>= 1) se += __shfl_xor(se, off);
    if (lane == 0) lseb[w][s] = mx + __logf(se);
  }
  __syncthreads();
  float a2 = (lane < 16) ? -lseb[w][lane] : -INFINITY;
  float mx2 = a2;
  for (int off = 32; off; off >>= 1) mx2 = fmaxf(mx2, __shfl_xor(mx2, off));
  float e2 = (lane < 16) ? expf(a2 - mx2) : 0.0f;
  for (int off = 32; off; off >>= 1) e2 += __shfl_xor(e2, off);
  float mc = mx2 + __logf(e2) - 2.7725887f;   // - log(16)
  float lmw = atomicAdd(lmacc + (g * 64 + lq) * 64 + lane, 0.0f);
  float lmv = -0.5f * (256.0f * F_LOG2PI + lmw);
  int row = pos[lq * 8 + g];
  out[row * 64 + lane] = lmv + mc;             // lmap is identity
}

// ---------------- launch ----------------
extern "C" void kernel_launch(void* const* d_in, const int* in_sizes, int n_in,
                              void* d_out, int out_size, void* d_ws, size_t ws_size,
                              hipStream_t stream) {
  (void)in_sizes; (void)n_in; (void)out_size; (void)ws_size;
  const float* P      = (const float*)d_in[0];   // (512, 512) f32
  const float* he     = (const float*)d_in[1];   // scalar
  const int*   labels = (const int*)d_in[2];     // (512,) int
  float* out = (float*)d_out;                    // (512, 64) f32

  float* ws = (float*)d_ws;
  float* accbuf = ws;                   // [8][64][16][64] = 524288 floats (2 MB)
  float* lmacc  = ws + 524288;          // [8][64][64] = 32768 floats
  float4* pq = (float4*)(ws + 557056);  // [2][256][64] float4 = 131072 floats
  float* cl  = ws + 688128;             // [2][64]
  int*   pos = (int*)(ws + 688256);     // [512]
  int*   lmp = pos + 512;               // [64]

  hipLaunchKernelGGL(k_protos, dim3(128),  dim3(256), 0, stream, P, he, labels, pq, cl,
                     (float4*)accbuf, (float4*)lmacc, pos, lmp);
  hipLaunchKernelGGL(k_tl,     dim3(2048), dim3(256), 0, stream, P, pos, pq, accbuf, lmacc,
                     cl, out);
}

// Round 5
// 355.448 us; speedup vs baseline: 1.0546x; 1.0267x over previous
//
#include <hip/hip_runtime.h>
#include <math.h>

// ---------------- sizes ----------------
#define DD 256
#define KK 512
#define LL 64
#define BB 8
#define SS 16
#define F_LOG2PI 1.83787706641f
#define PER_I 16777216u   // i-stride in per-half eps flat index (64*16*64*256)

typedef float v2f __attribute__((ext_vector_type(2)));

// ---------------- threefry2x32 (JAX-compatible) ----------------
// NOTE (R4 lesson): JAX partitionable RNG pins every eps element to
// x0^x1 of threefry2x32 at counter (0, flat_idx). The realization is
// bit-locked (absmax 0.125 == bf16 output quantization); using both output
// words / re-keying FAILS the check (R4: absmax 2.0). Do not touch bits.
struct U2 { unsigned x, y; };
struct U4 { unsigned a, b, c, d; };

__host__ __device__ constexpr U2 tf2x32(unsigned k0, unsigned k1, unsigned c0, unsigned c1) {
  unsigned ks2 = k0 ^ k1 ^ 0x1BD11BDAu;
  unsigned x0 = c0 + k0;
  unsigned x1 = c1 + k1;
#define TFR(r) { x0 += x1; x1 = (x1 << (r)) | (x1 >> (32 - (r))); x1 ^= x0; }
  TFR(13) TFR(15) TFR(26) TFR(6)   x0 += k1;  x1 += ks2 + 1u;
  TFR(17) TFR(29) TFR(16) TFR(24)  x0 += ks2; x1 += k0 + 2u;
  TFR(13) TFR(15) TFR(26) TFR(6)   x0 += k0;  x1 += k1 + 3u;
  TFR(17) TFR(29) TFR(16) TFR(24)  x0 += k1;  x1 += ks2 + 4u;
  TFR(13) TFR(15) TFR(26) TFR(6)   x0 += ks2; x1 += k0 + 5u;
#undef TFR
  return U2{x0, x1};
}

// Single-instruction rotate-left via v_alignbit_b32.
__device__ inline unsigned rotl(unsigned x, unsigned r) {
  return __builtin_amdgcn_alignbit(x, x, 32u - r);
}

// FOUR independent threefry folds advanced in lockstep. Identical bits to
// four sequential tf_fold calls (c0=0, k1 pre-folded into x1 init); the
// manual interleave forces ILP=4 on the otherwise fully-dependent ARX chain
// (R1 measured only ~45% of peak VALU issue: latency-bound, not issue-bound).
// Mid-stream key injections folded into the next round's add (v_add3_u32).
__device__ inline U4 tf_fold4(unsigned k0, unsigned k1, unsigned ks2,
                              unsigned x1a, unsigned x1b,
                              unsigned x1c, unsigned x1d) {
  unsigned x0a = k0, x0b = k0, x0c = k0, x0d = k0;
#define R4_(r) { x0a += x1a; x0b += x1b; x0c += x1c; x0d += x1d;               \
                 x1a = rotl(x1a, r); x1b = rotl(x1b, r);                        \
                 x1c = rotl(x1c, r); x1d = rotl(x1d, r);                        \
                 x1a ^= x0a; x1b ^= x0b; x1c ^= x0c; x1d ^= x0d; }
#define RI4_(r, kA, kB) {                                                       \
                 x1a += (kB); x1b += (kB); x1c += (kB); x1d += (kB);            \
                 x0a = x0a + (kA) + x1a; x0b = x0b + (kA) + x1b;                \
                 x0c = x0c + (kA) + x1c; x0d = x0d + (kA) + x1d;                \
                 x1a = rotl(x1a, r); x1b = rotl(x1b, r);                        \
                 x1c = rotl(x1c, r); x1d = rotl(x1d, r);                        \
                 x1a ^= x0a; x1b ^= x0b; x1c ^= x0c; x1d ^= x0d; }
  R4_(13u) R4_(15u) R4_(26u) R4_(6u)
  RI4_(17u, k1, ks2 + 1u)
  R4_(29u) R4_(16u) R4_(24u)
  RI4_(13u, ks2, k0 + 2u)
  R4_(15u) R4_(26u) R4_(6u)
  RI4_(17u, k0, k1 + 3u)
  R4_(29u) R4_(16u) R4_(24u)
  RI4_(13u, k1, ks2 + 4u)
  R4_(15u) R4_(26u) R4_(6u)
  x0a += ks2; x0b += ks2; x0c += ks2; x0d += ks2;
  x1a += k0 + 5u; x1b += k0 + 5u; x1c += k0 + 5u; x1d += k0 + 5u;
#undef R4_
#undef RI4_
  return U4{x0a ^ x1a, x0b ^ x1b, x0c ^ x1c, x0d ^ x1d};
}

// Packed fma helper: <2 x float> fma -> v_pk_fma_f32 on gfx90a+.
__device__ inline v2f pkfma(v2f a, v2f b, v2f c) {
#if __has_builtin(__builtin_elementwise_fma)
  return __builtin_elementwise_fma(a, b, c);
#else
  v2f r; r.x = fmaf(a.x, b.x, c.x); r.y = fmaf(a.y, b.y, c.y); return r;
#endif
}

// Two draws at once: bits -> {p*u, p*u}  (eps = sqrt2*p*u; sqrt2 folded into
// caller's scale). Low erfinv branch packed across the pair; high branch
// (w>=5) behind a wave-uniform __any, itself pk-paired.
__device__ inline v2f normal_pu2(unsigned b0, unsigned b1) {
  v2f fv;
  fv.x = __uint_as_float(__builtin_amdgcn_alignbit(128u, b0, 9u)); // (b>>9)|0x40000000
  fv.y = __uint_as_float(__builtin_amdgcn_alignbit(128u, b1, 9u));
  v2f uv = fv + (v2f){-3.0f, -3.0f};             // 2f-1 in [-1,1)
#if __has_builtin(__builtin_elementwise_max)
  uv = __builtin_elementwise_max(uv, (v2f){-0.99999994f, -0.99999994f});
#else
  uv.x = fmaxf(-0.99999994f, uv.x);
  uv.y = fmaxf(-0.99999994f, uv.y);
#endif
  v2f tv = pkfma(-uv, uv, (v2f){1.0f, 1.0f});    // 1 - u*u
  v2f lv;
  lv.x = __log2f(tv.x);
  lv.y = __log2f(tv.y);
  const v2f nln2 = {-0.69314718056f, -0.69314718056f};
  v2f wx = pkfma(lv, nln2, (v2f){-2.5f, -2.5f}); // w - 2.5
  v2f p; p.x = 2.81022636e-08f; p.y = 2.81022636e-08f;
  p = pkfma(p, wx, (v2f){ 3.43273939e-07f,  3.43273939e-07f});
  p = pkfma(p, wx, (v2f){-3.5233877e-06f,  -3.5233877e-06f});
  p = pkfma(p, wx, (v2f){-4.39150654e-06f, -4.39150654e-06f});
  p = pkfma(p, wx, (v2f){ 0.00021858087f,   0.00021858087f});
  p = pkfma(p, wx, (v2f){-0.00125372503f,  -0.00125372503f});
  p = pkfma(p, wx, (v2f){-0.00417768164f,  -0.00417768164f});
  p = pkfma(p, wx, (v2f){ 0.246640727f,     0.246640727f});
  p = pkfma(p, wx, (v2f){ 1.50140941f,      1.50140941f});
  v2f pu = p * uv;
  if (__any(fmaxf(wx.x, wx.y) >= 2.5f)) {        // any lane needs high branch
    v2f wv = lv * nln2;                          // w (same rounding as before)
    v2f sy;
    sy.x = __builtin_amdgcn_sqrtf(wv.x) - 3.0f;
    sy.y = __builtin_amdgcn_sqrtf(wv.y) - 3.0f;
    v2f q; q.x = -0.000200214257f; q.y = -0.000200214257f;
    q = pkfma(q, sy, (v2f){ 0.000100950558f,  0.000100950558f});
    q = pkfma(q, sy, (v2f){ 0.00134934322f,   0.00134934322f});
    q = pkfma(q, sy, (v2f){-0.00367342844f,  -0.00367342844f});
    q = pkfma(q, sy, (v2f){ 0.00573950773f,   0.00573950773f});
    q = pkfma(q, sy, (v2f){-0.0076224613f,   -0.0076224613f});
    q = pkfma(q, sy, (v2f){ 0.00943887047f,   0.00943887047f});
    q = pkfma(q, sy, (v2f){ 1.00167406f,      1.00167406f});
    q = pkfma(q, sy, (v2f){ 2.83297682f,      2.83297682f});
    v2f qu = q * uv;
    pu.x = (wx.x < 2.5f) ? pu.x : qu.x;
    pu.y = (wx.y < 2.5f) ? pu.y : qu.y;
  }
  return pu;
}

// ---------------- kernels ----------------

// Fused: counting-sort (recomputed per block, LDS-local) + prototype fusion
// + accbuf/lmacc zeroing. Block 0 publishes pos/lmap for k_tl/k_final.
__global__ void k_protos(const float* __restrict__ P, const float* __restrict__ he_p,
                         const int* __restrict__ labels, float4* __restrict__ pq,
                         float* __restrict__ cl, float4* __restrict__ accz,
                         float4* __restrict__ lmz, int* __restrict__ pos,
                         int* __restrict__ lmap) {
  int hb = blockIdx.x;             // h*64 + l
  int h = hb >> 6, l = hb & 63;
  int d = threadIdx.x;

  // zero accbuf (131072 float4 / 128 blocks / 256 thr = 4 each) and
  // lmacc (8192 float4: first 8192 global threads take one each)
  {
    float4 z; z.x = z.y = z.z = z.w = 0.0f;
    float4* base = accz + (hb * 256 + d) * 4;
#pragma unroll
    for (int j = 0; j < 4; ++j) base[j] = z;
    int gtid = hb * 256 + d;
    if (gtid < 8192) lmz[gtid] = z;
  }

  // ---- LDS counting-sort of balanced labels (robust to int64 labels) ----
  __shared__ int lab[512];
  __shared__ int cnt[64];
  __shared__ int mode;
  __shared__ int posl[512];
  if (d < 64) cnt[d] = 0;
  if (d == 0) mode = 0;
  __syncthreads();
  int v0 = labels[d], v1 = labels[d + 256];
  atomicAdd(&cnt[v0 & 63], 1);
  atomicAdd(&cnt[v1 & 63], 1);
  __syncthreads();
  if (d < 64 && cnt[d] != 8) mode = 1;   // benign same-value race
  __syncthreads();
  if (mode) { v0 = labels[2 * d]; v1 = labels[2 * (d + 256)]; }  // int64 LE low words
  lab[d] = v0 & 63; lab[d + 256] = v1 & 63;
  __syncthreads();
#pragma unroll
  for (int e = d; e < 512; e += 256) {
    int c = lab[e], o = 0;
    for (int j = 0; j < e; ++j) o += (lab[j] == c);
    posl[c * 8 + o] = e;               // idx of o-th occurrence of class c
  }
  __syncthreads();
  if (hb == 0) {                        // publish for k_tl / k_final
    pos[d] = posl[d]; pos[d + 256] = posl[d + 256];
    if (d < 64) lmap[d] = d;
  }

  // ---- prototype fusion ----
  float eps_var = expf(he_p[0]);
  int soff = h ? 0 : 4;            // support rows for this half
  float sinv = 0.f, sminv = 0.f;
#pragma unroll
  for (int j = 0; j < 4; ++j) {
    int row = posl[l * 8 + soff + j];
    float m = P[row * KK + d];
    float hh = P[row * KK + DD + d];
    float vv = eps_var + expf(hh);
    float iv = 1.0f / vv;
    sinv += iv; sminv += m * iv;
  }
  float nv = 1.0f / sinv;
  float nm = nv * sminv;
  float ev = eps_var + nv;         // exp(h_proto)
  // .z = rsqrt(ev) so k_tl needs no per-dd sqrt for sivp (R3-verified).
  float4 rec; rec.x = nm; rec.y = ev;
  rec.z = __builtin_amdgcn_rcpf(__builtin_amdgcn_sqrtf(ev));
  rec.w = 0.0f;
  pq[(h * 256 + d) * 64 + l] = rec;
  float t = F_LOG2PI + __logf(ev);
  for (int off = 32; off; off >>= 1) t += __shfl_xor(t, off);
  __shared__ float red[4];
  int w = d >> 6, lane = d & 63;
  if (lane == 0) red[w] = t;
  __syncthreads();
  if (d == 0) cl[hb] = red[0] + red[1] + red[2] + red[3];
}

// Hot kernel (R1 structure + 4-way chain interleave): block=(h, lq, dchunk
// of 16). wave w = query i, lane = lp. 16 threefry chains per dd, advanced
// as 4 quads in lockstep for ILP. Bits identical to R1 (JAX partitionable).
// Also accumulates the lm (logmls) partial over its 16-d slice into lmacc.
__global__ __launch_bounds__(256) void k_tl(const float* __restrict__ P,
    const int* __restrict__ pos, const float4* __restrict__ pq,
    float* __restrict__ accbuf, float* __restrict__ lmacc) {
  constexpr U2 S1 = tf2x32(0u, 42u, 0u, 0u);  // foldlike split of key(42)
  constexpr U2 S2 = tf2x32(0u, 42u, 0u, 1u);
  int bb = blockIdx.x;             // h*1024 + lq*16 + chunk
  int h = bb >> 10;
  int lq = (bb >> 4) & 63;
  int chunk = bb & 15;
  int t = threadIdx.x;

  __shared__ float2 q[4 * 256];    // [i][d] = {m, exp(h)}
#pragma unroll
  for (int i = 0; i < 4; ++i) {
    int row = pos[lq * 8 + h * 4 + i];
    float2 rec;
    rec.x = P[row * KK + t];
    rec.y = expf(P[row * KK + DD + t]);
    q[i * 256 + t] = rec;
  }
  __syncthreads();

  int w = t >> 6, lane = t & 63;   // w = query i, lane = lp
  unsigned k0 = h ? S2.x : S1.x;
  unsigned k1 = h ? S2.y : S1.y;
  unsigned ks2 = k0 ^ k1 ^ 0x1BD11BDAu;
  // eps flat idx (per half) = i*PER_I + lq*262144 + s*16384 + lp*256 + d
  // k1 folded into the counter base (threefry x1 init = c1 + k1).
  unsigned ebk = (unsigned)w * PER_I + (unsigned)lq * 262144u +
                 (unsigned)lane * 256u + (unsigned)chunk * 16u + k1;
  const float2* qd = &q[w * 256];
  const float4* pp = pq + (h * 256 + chunk * 16) * 64 + lane;
  int g = h * 4 + w;
  float* dst = accbuf + ((g * 64 + lq) * 16) * 64 + lane;

  v2f acc2[8];
#pragma unroll
  for (int sp = 0; sp < 8; ++sp) { acc2[sp].x = 0.0f; acc2[sp].y = 0.0f; }
  float lmpart = 0.0f;             // partial of sum_d(log vs + diff^2/vs)

#pragma unroll 1
  for (int dd = 0; dd < 16; ++dd) {
    float4 pr = pp[dd * 64];           // {mp, ev, rsqrt(ev), -} coalesced, L2-hot
    float2 qv = qd[chunk * 16 + dd];   // broadcast ds_read_b64
    float vs  = qv.y + pr.y;
    float ivs = __builtin_amdgcn_rcpf(vs);
    float evs = pr.y * ivs;            // ev/vs
    float sivp = pr.z;                 // rsqrt(ev), precomputed in k_protos
    float dif = qv.x - pr.x;
    lmpart += __logf(vs) + dif * dif * ivs;              // lm term
    float A = dif * evs * sivp;                          // sign irrelevant (squared)
    float S = __builtin_amdgcn_sqrtf(qv.y * evs) * sivp * 1.41421356f; // sqrt2 folded
    v2f Av; Av.x = A; Av.y = A;
    v2f Sv; Sv.x = S; Sv.y = S;
    unsigned ebkd = ebk + (unsigned)dd;
#pragma unroll
    for (int sq = 0; sq < 4; ++sq) {
      unsigned b0 = ebkd + (unsigned)(4 * sq) * 16384u;
      U4 r = tf_fold4(k0, k1, ks2, b0, b0 + 16384u,
                      b0 + 2u * 16384u, b0 + 3u * 16384u);
      v2f pu01 = normal_pu2(r.a, r.b);
      v2f pu23 = normal_pu2(r.c, r.d);
      v2f d01 = pkfma(Sv, pu01, Av);
      v2f d23 = pkfma(Sv, pu23, Av);
      acc2[2 * sq]     = pkfma(d01, d01, acc2[2 * sq]);
      acc2[2 * sq + 1] = pkfma(d23, d23, acc2[2 * sq + 1]);
    }
  }
#pragma unroll
  for (int sp = 0; sp < 8; ++sp) {
    atomicAdd(dst + (2 * sp) * 64, acc2[sp].x);
    atomicAdd(dst + (2 * sp + 1) * 64, acc2[sp].y);
  }
  atomicAdd(lmacc + (g * 64 + lq) * 64 + lane, lmpart);
}

// Merged epilogue: per (g,lq): 16 lse over lp (wave w does s=w*4..w*4+3),
// MC = logsumexp_s(-lse) - log S, lm = -0.5*(256*log2pi + lmacc), scatter.
__global__ void k_final(const float* __restrict__ lmacc, const float* __restrict__ accbuf,
                        const float* __restrict__ cl, const int* __restrict__ pos,
                        const int* __restrict__ lmap, float* __restrict__ out) {
  int bb = blockIdx.x;             // g*64 + lq
  int g = bb >> 6, lq = bb & 63;
  int h = g >> 2;
  int t = threadIdx.x, w = t >> 6, lane = t & 63;
  __shared__ float lsebuf[16];
  float clv = cl[h * 64 + lane];
#pragma unroll
  for (int j = 0; j < 4; ++j) {
    int s = w * 4 + j;
    float tlv = -0.5f * (clv + accbuf[(bb * 16 + s) * 64 + lane]);
    float mx = tlv;
    for (int off = 32; off; off >>= 1) mx = fmaxf(mx, __shfl_xor(mx, off));
    float se = expf(tlv - mx);
    for (int off = 32; off; off >>= 1) se += __shfl_xor(se, off);
    if (lane == 0) lsebuf[s] = mx + __logf(se);
  }
  __syncthreads();
  if (t < 64) {
    float a = (t < 16) ? -lsebuf[t] : -INFINITY;
    float mx = a;
    for (int off = 32; off; off >>= 1) mx = fmaxf(mx, __shfl_xor(mx, off));
    float e = (t < 16) ? expf(a - mx) : 0.0f;
    for (int off = 32; off; off >>= 1) e += __shfl_xor(e, off);
    float mc = mx + __logf(e) - 2.7725887f;   // - log(16)
    float lmv = -0.5f * (256.0f * F_LOG2PI + lmacc[bb * 64 + t]);
    int row = pos[lq * 8 + g];
    out[row * 64 + lmap[t]] = lmv + mc;
  }
}

// ---------------- launch ----------------
extern "C" void kernel_launch(void* const* d_in, const int* in_sizes, int n_in,
                              void* d_out, int out_size, void* d_ws, size_t ws_size,
                              hipStream_t stream) {
  (void)in_sizes; (void)n_in; (void)out_size; (void)ws_size;
  const float* P      = (const float*)d_in[0];   // (512, 512) f32
  const float* he     = (const float*)d_in[1];   // scalar
  const int*   labels = (const int*)d_in[2];     // (512,) int
  float* out = (float*)d_out;                    // (512, 64) f32

  float* ws = (float*)d_ws;
  float* accbuf = ws;                   // [8][64][16][64] = 524288 floats (2 MB)
  float* lmacc  = ws + 524288;          // [8][64][64] = 32768 floats
  float4* pq = (float4*)(ws + 557056);  // [2][256][64] float4 = 131072 floats
  float* cl  = ws + 688128;             // [2][64]
  int*   pos = (int*)(ws + 688256);     // [512]
  int*   lmp = pos + 512;               // [64]

  hipLaunchKernelGGL(k_protos, dim3(128),  dim3(256), 0, stream, P, he, labels, pq, cl,
                     (float4*)accbuf, (float4*)lmacc, pos, lmp);
  hipLaunchKernelGGL(k_tl,     dim3(2048), dim3(256), 0, stream, P, pos, pq, accbuf, lmacc);
  hipLaunchKernelGGL(k_final,  dim3(512),  dim3(256), 0, stream, lmacc, accbuf, cl, pos, lmp, out);
}

// Round 6
// 354.321 us; speedup vs baseline: 1.0580x; 1.0032x over previous
//
#include <hip/hip_runtime.h>
#include <math.h>

// ---------------- sizes ----------------
#define DD 256
#define KK 512
#define LL 64
#define BB 8
#define SS 16
#define F_LOG2PI 1.83787706641f
#define PER_I 16777216u   // i-stride in per-half eps flat index (64*16*64*256)

typedef float v2f __attribute__((ext_vector_type(2)));

// ---------------- threefry2x32 (JAX-compatible) ----------------
// NOTE (R4 lesson): JAX partitionable RNG pins every eps element to
// x0^x1 of threefry2x32 at counter (0, flat_idx). The realization is
// bit-locked (absmax 0.125 == bf16 output quantization); using both output
// words / re-keying FAILS the check (R4: absmax 2.0). Do not touch bits.
struct U2 { unsigned x, y; };
struct U4 { unsigned a, b, c, d; };

__host__ __device__ constexpr U2 tf2x32(unsigned k0, unsigned k1, unsigned c0, unsigned c1) {
  unsigned ks2 = k0 ^ k1 ^ 0x1BD11BDAu;
  unsigned x0 = c0 + k0;
  unsigned x1 = c1 + k1;
#define TFR(r) { x0 += x1; x1 = (x1 << (r)) | (x1 >> (32 - (r))); x1 ^= x0; }
  TFR(13) TFR(15) TFR(26) TFR(6)   x0 += k1;  x1 += ks2 + 1u;
  TFR(17) TFR(29) TFR(16) TFR(24)  x0 += ks2; x1 += k0 + 2u;
  TFR(13) TFR(15) TFR(26) TFR(6)   x0 += k0;  x1 += k1 + 3u;
  TFR(17) TFR(29) TFR(16) TFR(24)  x0 += k1;  x1 += ks2 + 4u;
  TFR(13) TFR(15) TFR(26) TFR(6)   x0 += ks2; x1 += k0 + 5u;
#undef TFR
  return U2{x0, x1};
}

// Single-instruction rotate-left via v_alignbit_b32.
__device__ inline unsigned rotl(unsigned x, unsigned r) {
  return __builtin_amdgcn_alignbit(x, x, 32u - r);
}

// FOUR independent threefry folds advanced in lockstep. Identical bits to
// four sequential tf_fold calls (c0=0, k1 pre-folded into x1 init). R5
// lesson: this interleave needs >32 VGPRs to survive regalloc; paired with
// __launch_bounds__(256,4) (VGPR cap 128) so the 4 streams stay live.
// Mid-stream key injections folded into the next round's add (v_add3_u32).
__device__ inline U4 tf_fold4(unsigned k0, unsigned k1, unsigned ks2,
                              unsigned x1a, unsigned x1b,
                              unsigned x1c, unsigned x1d) {
  unsigned x0a = k0, x0b = k0, x0c = k0, x0d = k0;
#define R4_(r) { x0a += x1a; x0b += x1b; x0c += x1c; x0d += x1d;               \
                 x1a = rotl(x1a, r); x1b = rotl(x1b, r);                        \
                 x1c = rotl(x1c, r); x1d = rotl(x1d, r);                        \
                 x1a ^= x0a; x1b ^= x0b; x1c ^= x0c; x1d ^= x0d; }
#define RI4_(r, kA, kB) {                                                       \
                 x1a += (kB); x1b += (kB); x1c += (kB); x1d += (kB);            \
                 x0a = x0a + (kA) + x1a; x0b = x0b + (kA) + x1b;                \
                 x0c = x0c + (kA) + x1c; x0d = x0d + (kA) + x1d;                \
                 x1a = rotl(x1a, r); x1b = rotl(x1b, r);                        \
                 x1c = rotl(x1c, r); x1d = rotl(x1d, r);                        \
                 x1a ^= x0a; x1b ^= x0b; x1c ^= x0c; x1d ^= x0d; }
  R4_(13u) R4_(15u) R4_(26u) R4_(6u)
  RI4_(17u, k1, ks2 + 1u)
  R4_(29u) R4_(16u) R4_(24u)
  RI4_(13u, ks2, k0 + 2u)
  R4_(15u) R4_(26u) R4_(6u)
  RI4_(17u, k0, k1 + 3u)
  R4_(29u) R4_(16u) R4_(24u)
  RI4_(13u, k1, ks2 + 4u)
  R4_(15u) R4_(26u) R4_(6u)
  x0a += ks2; x0b += ks2; x0c += ks2; x0d += ks2;
  x1a += k0 + 5u; x1b += k0 + 5u; x1c += k0 + 5u; x1d += k0 + 5u;
#undef R4_
#undef RI4_
  return U4{x0a ^ x1a, x0b ^ x1b, x0c ^ x1c, x0d ^ x1d};
}

// Packed fma helper: <2 x float> fma -> v_pk_fma_f32 on gfx90a+.
__device__ inline v2f pkfma(v2f a, v2f b, v2f c) {
#if __has_builtin(__builtin_elementwise_fma)
  return __builtin_elementwise_fma(a, b, c);
#else
  v2f r; r.x = fmaf(a.x, b.x, c.x); r.y = fmaf(a.y, b.y, c.y); return r;
#endif
}

// Two draws at once: bits -> {p*u, p*u}  (eps = sqrt2*p*u; sqrt2 folded into
// caller's scale). Low erfinv branch packed across the pair; high branch
// (w>=5) behind a wave-uniform __any, itself pk-paired.
__device__ inline v2f normal_pu2(unsigned b0, unsigned b1) {
  v2f fv;
  fv.x = __uint_as_float(__builtin_amdgcn_alignbit(128u, b0, 9u)); // (b>>9)|0x40000000
  fv.y = __uint_as_float(__builtin_amdgcn_alignbit(128u, b1, 9u));
  v2f uv = fv + (v2f){-3.0f, -3.0f};             // 2f-1 in [-1,1)
#if __has_builtin(__builtin_elementwise_max)
  uv = __builtin_elementwise_max(uv, (v2f){-0.99999994f, -0.99999994f});
#else
  uv.x = fmaxf(-0.99999994f, uv.x);
  uv.y = fmaxf(-0.99999994f, uv.y);
#endif
  v2f tv = pkfma(-uv, uv, (v2f){1.0f, 1.0f});    // 1 - u*u
  v2f lv;
  lv.x = __log2f(tv.x);
  lv.y = __log2f(tv.y);
  const v2f nln2 = {-0.69314718056f, -0.69314718056f};
  v2f wx = pkfma(lv, nln2, (v2f){-2.5f, -2.5f}); // w - 2.5
  v2f p; p.x = 2.81022636e-08f; p.y = 2.81022636e-08f;
  p = pkfma(p, wx, (v2f){ 3.43273939e-07f,  3.43273939e-07f});
  p = pkfma(p, wx, (v2f){-3.5233877e-06f,  -3.5233877e-06f});
  p = pkfma(p, wx, (v2f){-4.39150654e-06f, -4.39150654e-06f});
  p = pkfma(p, wx, (v2f){ 0.00021858087f,   0.00021858087f});
  p = pkfma(p, wx, (v2f){-0.00125372503f,  -0.00125372503f});
  p = pkfma(p, wx, (v2f){-0.00417768164f,  -0.00417768164f});
  p = pkfma(p, wx, (v2f){ 0.246640727f,     0.246640727f});
  p = pkfma(p, wx, (v2f){ 1.50140941f,      1.50140941f});
  v2f pu = p * uv;
  if (__any(fmaxf(wx.x, wx.y) >= 2.5f)) {        // any lane needs high branch
    v2f wv = lv * nln2;                          // w (same rounding as before)
    v2f sy;
    sy.x = __builtin_amdgcn_sqrtf(wv.x) - 3.0f;
    sy.y = __builtin_amdgcn_sqrtf(wv.y) - 3.0f;
    v2f q; q.x = -0.000200214257f; q.y = -0.000200214257f;
    q = pkfma(q, sy, (v2f){ 0.000100950558f,  0.000100950558f});
    q = pkfma(q, sy, (v2f){ 0.00134934322f,   0.00134934322f});
    q = pkfma(q, sy, (v2f){-0.00367342844f,  -0.00367342844f});
    q = pkfma(q, sy, (v2f){ 0.00573950773f,   0.00573950773f});
    q = pkfma(q, sy, (v2f){-0.0076224613f,   -0.0076224613f});
    q = pkfma(q, sy, (v2f){ 0.00943887047f,   0.00943887047f});
    q = pkfma(q, sy, (v2f){ 1.00167406f,      1.00167406f});
    q = pkfma(q, sy, (v2f){ 2.83297682f,      2.83297682f});
    v2f qu = q * uv;
    pu.x = (wx.x < 2.5f) ? pu.x : qu.x;
    pu.y = (wx.y < 2.5f) ? pu.y : qu.y;
  }
  return pu;
}

// ---------------- kernels ----------------

// Fused: counting-sort (recomputed per block, LDS-local) + prototype fusion
// + accbuf/lmacc zeroing. Block 0 publishes pos/lmap for k_tl/k_final.
__global__ void k_protos(const float* __restrict__ P, const float* __restrict__ he_p,
                         const int* __restrict__ labels, float4* __restrict__ pq,
                         float* __restrict__ cl, float4* __restrict__ accz,
                         float4* __restrict__ lmz, int* __restrict__ pos,
                         int* __restrict__ lmap) {
  int hb = blockIdx.x;             // h*64 + l
  int h = hb >> 6, l = hb & 63;
  int d = threadIdx.x;

  // zero accbuf (131072 float4 / 128 blocks / 256 thr = 4 each) and
  // lmacc (8192 float4: first 8192 global threads take one each)
  {
    float4 z; z.x = z.y = z.z = z.w = 0.0f;
    float4* base = accz + (hb * 256 + d) * 4;
#pragma unroll
    for (int j = 0; j < 4; ++j) base[j] = z;
    int gtid = hb * 256 + d;
    if (gtid < 8192) lmz[gtid] = z;
  }

  // ---- LDS counting-sort of balanced labels (robust to int64 labels) ----
  __shared__ int lab[512];
  __shared__ int cnt[64];
  __shared__ int mode;
  __shared__ int posl[512];
  if (d < 64) cnt[d] = 0;
  if (d == 0) mode = 0;
  __syncthreads();
  int v0 = labels[d], v1 = labels[d + 256];
  atomicAdd(&cnt[v0 & 63], 1);
  atomicAdd(&cnt[v1 & 63], 1);
  __syncthreads();
  if (d < 64 && cnt[d] != 8) mode = 1;   // benign same-value race
  __syncthreads();
  if (mode) { v0 = labels[2 * d]; v1 = labels[2 * (d + 256)]; }  // int64 LE low words
  lab[d] = v0 & 63; lab[d + 256] = v1 & 63;
  __syncthreads();
#pragma unroll
  for (int e = d; e < 512; e += 256) {
    int c = lab[e], o = 0;
    for (int j = 0; j < e; ++j) o += (lab[j] == c);
    posl[c * 8 + o] = e;               // idx of o-th occurrence of class c
  }
  __syncthreads();
  if (hb == 0) {                        // publish for k_tl / k_final
    pos[d] = posl[d]; pos[d + 256] = posl[d + 256];
    if (d < 64) lmap[d] = d;
  }

  // ---- prototype fusion ----
  float eps_var = expf(he_p[0]);
  int soff = h ? 0 : 4;            // support rows for this half
  float sinv = 0.f, sminv = 0.f;
#pragma unroll
  for (int j = 0; j < 4; ++j) {
    int row = posl[l * 8 + soff + j];
    float m = P[row * KK + d];
    float hh = P[row * KK + DD + d];
    float vv = eps_var + expf(hh);
    float iv = 1.0f / vv;
    sinv += iv; sminv += m * iv;
  }
  float nv = 1.0f / sinv;
  float nm = nv * sminv;
  float ev = eps_var + nv;         // exp(h_proto)
  // .z = rsqrt(ev) so k_tl needs no per-dd sqrt for sivp (R3-verified).
  float4 rec; rec.x = nm; rec.y = ev;
  rec.z = __builtin_amdgcn_rcpf(__builtin_amdgcn_sqrtf(ev));
  rec.w = 0.0f;
  pq[(h * 256 + d) * 64 + l] = rec;
  float t = F_LOG2PI + __logf(ev);
  for (int off = 32; off; off >>= 1) t += __shfl_xor(t, off);
  __shared__ float red[4];
  int w = d >> 6, lane = d & 63;
  if (lane == 0) red[w] = t;
  __syncthreads();
  if (d == 0) cl[hb] = red[0] + red[1] + red[2] + red[3];
}

// Hot kernel (R5 structure + VGPR headroom): block=(h, lq, dchunk of 16).
// wave w = query i, lane = lp. 16 threefry chains per dd, advanced as 4
// quads in lockstep for ILP. __launch_bounds__(256,4) raises the VGPR cap
// 32->128 so the 4 chain states + 16 accumulators stay live (R5 showed the
// 32-VGPR default re-serializes the interleave). Bits identical to R1.
__global__ __launch_bounds__(256, 4) void k_tl(const float* __restrict__ P,
    const int* __restrict__ pos, const float4* __restrict__ pq,
    float* __restrict__ accbuf, float* __restrict__ lmacc) {
  constexpr U2 S1 = tf2x32(0u, 42u, 0u, 0u);  // foldlike split of key(42)
  constexpr U2 S2 = tf2x32(0u, 42u, 0u, 1u);
  int bb = blockIdx.x;             // h*1024 + lq*16 + chunk
  int h = bb >> 10;
  int lq = (bb >> 4) & 63;
  int chunk = bb & 15;
  int t = threadIdx.x;

  __shared__ float2 q[4 * 256];    // [i][d] = {m, exp(h)}
#pragma unroll
  for (int i = 0; i < 4; ++i) {
    int row = pos[lq * 8 + h * 4 + i];
    float2 rec;
    rec.x = P[row * KK + t];
    rec.y = expf(P[row * KK + DD + t]);
    q[i * 256 + t] = rec;
  }
  __syncthreads();

  int w = t >> 6, lane = t & 63;   // w = query i, lane = lp
  unsigned k0 = h ? S2.x : S1.x;
  unsigned k1 = h ? S2.y : S1.y;
  unsigned ks2 = k0 ^ k1 ^ 0x1BD11BDAu;
  // eps flat idx (per half) = i*PER_I + lq*262144 + s*16384 + lp*256 + d
  // k1 folded into the counter base (threefry x1 init = c1 + k1).
  unsigned ebk = (unsigned)w * PER_I + (unsigned)lq * 262144u +
                 (unsigned)lane * 256u + (unsigned)chunk * 16u + k1;
  const float2* qd = &q[w * 256];
  const float4* pp = pq + (h * 256 + chunk * 16) * 64 + lane;
  int g = h * 4 + w;
  float* dst = accbuf + ((g * 64 + lq) * 16) * 64 + lane;

  v2f acc2[8];
#pragma unroll
  for (int sp = 0; sp < 8; ++sp) { acc2[sp].x = 0.0f; acc2[sp].y = 0.0f; }
  float lmpart = 0.0f;             // partial of sum_d(log vs + diff^2/vs)

#pragma unroll 1
  for (int dd = 0; dd < 16; ++dd) {
    float4 pr = pp[dd * 64];           // {mp, ev, rsqrt(ev), -} coalesced, L2-hot
    float2 qv = qd[chunk * 16 + dd];   // broadcast ds_read_b64
    float vs  = qv.y + pr.y;
    float ivs = __builtin_amdgcn_rcpf(vs);
    float evs = pr.y * ivs;            // ev/vs
    float sivp = pr.z;                 // rsqrt(ev), precomputed in k_protos
    float dif = qv.x - pr.x;
    lmpart += __logf(vs) + dif * dif * ivs;              // lm term
    float A = dif * evs * sivp;                          // sign irrelevant (squared)
    float S = __builtin_amdgcn_sqrtf(qv.y * evs) * sivp * 1.41421356f; // sqrt2 folded
    v2f Av; Av.x = A; Av.y = A;
    v2f Sv; Sv.x = S; Sv.y = S;
    unsigned ebkd = ebk + (unsigned)dd;
#pragma unroll
    for (int sq = 0; sq < 4; ++sq) {
      unsigned b0 = ebkd + (unsigned)(4 * sq) * 16384u;
      U4 r = tf_fold4(k0, k1, ks2, b0, b0 + 16384u,
                      b0 + 2u * 16384u, b0 + 3u * 16384u);
      v2f pu01 = normal_pu2(r.a, r.b);
      v2f pu23 = normal_pu2(r.c, r.d);
      v2f d01 = pkfma(Sv, pu01, Av);
      v2f d23 = pkfma(Sv, pu23, Av);
      acc2[2 * sq]     = pkfma(d01, d01, acc2[2 * sq]);
      acc2[2 * sq + 1] = pkfma(d23, d23, acc2[2 * sq + 1]);
    }
  }
#pragma unroll
  for (int sp = 0; sp < 8; ++sp) {
    atomicAdd(dst + (2 * sp) * 64, acc2[sp].x);
    atomicAdd(dst + (2 * sp + 1) * 64, acc2[sp].y);
  }
  atomicAdd(lmacc + (g * 64 + lq) * 64 + lane, lmpart);
}

// Merged epilogue: per (g,lq): 16 lse over lp (wave w does s=w*4..w*4+3),
// MC = logsumexp_s(-lse) - log S, lm = -0.5*(256*log2pi + lmacc), scatter.
__global__ void k_final(const float* __restrict__ lmacc, const float* __restrict__ accbuf,
                        const float* __restrict__ cl, const int* __restrict__ pos,
                        const int* __restrict__ lmap, float* __restrict__ out) {
  int bb = blockIdx.x;             // g*64 + lq
  int g = bb >> 6, lq = bb & 63;
  int h = g >> 2;
  int t = threadIdx.x, w = t >> 6, lane = t & 63;
  __shared__ float lsebuf[16];
  float clv = cl[h * 64 + lane];
#pragma unroll
  for (int j = 0; j < 4; ++j) {
    int s = w * 4 + j;
    float tlv = -0.5f * (clv + accbuf[(bb * 16 + s) * 64 + lane]);
    float mx = tlv;
    for (int off = 32; off; off >>= 1) mx = fmaxf(mx, __shfl_xor(mx, off));
    float se = expf(tlv - mx);
    for (int off = 32; off; off >>= 1) se += __shfl_xor(se, off);
    if (lane == 0) lsebuf[s] = mx + __logf(se);
  }
  __syncthreads();
  if (t < 64) {
    float a = (t < 16) ? -lsebuf[t] : -INFINITY;
    float mx = a;
    for (int off = 32; off; off >>= 1) mx = fmaxf(mx, __shfl_xor(mx, off));
    float e = (t < 16) ? expf(a - mx) : 0.0f;
    for (int off = 32; off; off >>= 1) e += __shfl_xor(e, off);
    float mc = mx + __logf(e) - 2.7725887f;   // - log(16)
    float lmv = -0.5f * (256.0f * F_LOG2PI + lmacc[bb * 64 + t]);
    int row = pos[lq * 8 + g];
    out[row * 64 + lmap[t]] = lmv + mc;
  }
}

// ---------------- launch ----------------
extern "C" void kernel_launch(void* const* d_in, const int* in_sizes, int n_in,
                              void* d_out, int out_size, void* d_ws, size_t ws_size,
                              hipStream_t stream) {
  (void)in_sizes; (void)n_in; (void)out_size; (void)ws_size;
  const float* P      = (const float*)d_in[0];   // (512, 512) f32
  const float* he     = (const float*)d_in[1];   // scalar
  const int*   labels = (const int*)d_in[2];     // (512,) int
  float* out = (float*)d_out;                    // (512, 64) f32

  float* ws = (float*)d_ws;
  float* accbuf = ws;                   // [8][64][16][64] = 524288 floats (2 MB)
  float* lmacc  = ws + 524288;          // [8][64][64] = 32768 floats
  float4* pq = (float4*)(ws + 557056);  // [2][256][64] float4 = 131072 floats
  float* cl  = ws + 688128;             // [2][64]
  int*   pos = (int*)(ws + 688256);     // [512]
  int*   lmp = pos + 512;               // [64]

  hipLaunchKernelGGL(k_protos, dim3(128),  dim3(256), 0, stream, P, he, labels, pq, cl,
                     (float4*)accbuf, (float4*)lmacc, pos, lmp);
  hipLaunchKernelGGL(k_tl,     dim3(2048), dim3(256), 0, stream, P, pos, pq, accbuf, lmacc);
  hipLaunchKernelGGL(k_final,  dim3(512),  dim3(256), 0, stream, lmacc, accbuf, cl, pos, lmp, out);
}